// Round 2
// baseline (307.866 us; speedup 1.0000x reference)
//
#include <hip/hip_runtime.h>

typedef unsigned int uint_t;
typedef unsigned short u16;
typedef __attribute__((ext_vector_type(4))) float f32x4;
typedef __attribute__((ext_vector_type(8))) __bf16 bf16x8;

#define S_TOT 20000
#define S_LD  20032   // padded V^T row stride
#define B_TOT 1024
#define NHEAD 4
#define NSPLIT 16
#define NCHUNK 313    // ceil(20000/64)

__device__ __forceinline__ u16 f2bf(float x) {
  uint_t u = __builtin_bit_cast(uint_t, x);
  u += 0x7FFFu + ((u >> 16) & 1u);
  return (u16)(u >> 16);
}

__device__ __forceinline__ uint_t cvtpk(float lo, float hi) {
  uint_t r;
  asm("v_cvt_pk_bf16_f32 %0, %1, %2" : "=v"(r) : "v"(lo), "v"(hi));
  return r;
}

__device__ __forceinline__ bf16x8 ld_frag(const u16* p) {
  return __builtin_bit_cast(bf16x8, *(const uint4*)p);
}

// ---------------- conversions f32 -> bf16 ----------------
__global__ void convert_all(const float* __restrict__ ipw, const float* __restrict__ opw,
                            const float* __restrict__ nc,
                            u16* __restrict__ wqkv, u16* __restrict__ wout, u16* __restrict__ ncb) {
  int i = blockIdx.x * 256 + threadIdx.x;           // 0..524287
  if (i < 196608)      wqkv[i] = f2bf(ipw[i]);
  else if (i < 262144) wout[i - 196608] = f2bf(opw[i - 196608]);
  else                 ncb[i - 262144] = f2bf(nc[i - 262144]);
}

__global__ void convert_emb(const float* __restrict__ emb, u16* __restrict__ embb) {
  size_t i = (size_t)(blockIdx.x * 256 + threadIdx.x) * 4;   // 5000*256*4 = 5.12M
  float4 v = *(const float4*)(emb + i);
  uint2 o;
  o.x = f2bf(v.x) | ((uint_t)f2bf(v.y) << 16);
  o.y = f2bf(v.z) | ((uint_t)f2bf(v.w) << 16);
  *(uint2*)(embb + i) = o;
}

// zero the padded tail columns of V^T (s in [20000,20032))
__global__ void zero_vt_pad(u16* __restrict__ vt) {
  int i = blockIdx.x * 256 + threadIdx.x;           // 8192 = 256 rows * 32
  int d = i >> 5, j = i & 31;
  vt[(size_t)d * S_LD + S_TOT + j] = 0;
}

// ---------------- column mean of embed (deterministic 2-stage) ----------------
__global__ void colmean_part(const float* __restrict__ emb, float* __restrict__ cmp) {
  int t = threadIdx.x, p = blockIdx.x;              // 80 blocks x 250 rows
  float s = 0.f;
  for (int r = p * 250; r < (p + 1) * 250; r++) s += emb[(size_t)r * 256 + t];
  cmp[p * 256 + t] = s;
}

__global__ void vmean_k(const float* __restrict__ cmp, const float* __restrict__ ipw,
                        const float* __restrict__ ipb, float* __restrict__ vm) {
  __shared__ float sm[256];
  int t = threadIdx.x;
  float s = 0.f;
  for (int p = 0; p < 80; p++) s += cmp[p * 256 + t];
  sm[t] = s * (1.0f / 20000.0f);
  __syncthreads();
  float acc = ipb[512 + t];
  const float* wv = ipw + (size_t)(512 + t) * 256;
  for (int c = 0; c < 256; c++) acc += sm[c] * wv[c];
  vm[t] = acc;
}

// ---------------- generic B^T GEMM: C[M x N] = A_bf16[M x 256] @ W_bf16[N x 256]^T + bias ----
// MODE 0: out bf16 row-major [M][256]        (q projection)
// MODE 1: n<256 -> K bf16 [M][256]; n>=256 -> V^T bf16 [(n-256)][S_LD] (kv projection)
// MODE 2: out f32 row-major [M][256]         (output projection)
template<int MODE>
__launch_bounds__(256)
__global__ void gemm_bt(const u16* __restrict__ A, const u16* __restrict__ W,
                        const float* __restrict__ bias, int M,
                        u16* __restrict__ ob, u16* __restrict__ kb,
                        u16* __restrict__ vtb, float* __restrict__ of) {
  __shared__ __align__(16) u16 sA[64][40];
  __shared__ __align__(16) u16 sW[64][40];
  const int t = threadIdx.x;
  const int w = t >> 6, lane = t & 63, lr = lane & 15, lg = lane >> 4;
  const int m0 = blockIdx.x * 64, n0 = blockIdx.y * 64;
  const int r = t >> 2, kc = (t & 3) * 8;
  f32x4 acc[4] = {};
  int ga = m0 + r; if (ga > M - 1) ga = M - 1;
  const u16* ap = A + (size_t)ga * 256;
  const u16* wp = W + (size_t)(n0 + r) * 256;
  for (int k0 = 0; k0 < 256; k0 += 32) {
    *(uint4*)&sA[r][kc] = *(const uint4*)(ap + k0 + kc);
    *(uint4*)&sW[r][kc] = *(const uint4*)(wp + k0 + kc);
    __syncthreads();
    bf16x8 af = ld_frag(&sA[16 * w + lr][lg * 8]);
#pragma unroll
    for (int nf = 0; nf < 4; nf++) {
      bf16x8 bfr = ld_frag(&sW[16 * nf + lr][lg * 8]);
      acc[nf] = __builtin_amdgcn_mfma_f32_16x16x32_bf16(af, bfr, acc[nf], 0, 0, 0);
    }
    __syncthreads();
  }
  const int rbase = m0 + 16 * w + lg * 4;
#pragma unroll
  for (int nf = 0; nf < 4; nf++) {
    const int n = n0 + nf * 16 + lr;
    const float bi = bias[n];
    if (MODE == 1) {
      if (n >= 256) {
        const int vr = n - 256;
        u16 b[4];
#pragma unroll
        for (int g = 0; g < 4; g++) b[g] = f2bf(acc[nf][g] + bi);
        if (rbase + 3 < M) {
          uint2 p2; p2.x = b[0] | ((uint_t)b[1] << 16); p2.y = b[2] | ((uint_t)b[3] << 16);
          *(uint2*)&vtb[(size_t)vr * S_LD + rbase] = p2;
        } else {
#pragma unroll
          for (int g = 0; g < 4; g++) if (rbase + g < M) vtb[(size_t)vr * S_LD + rbase + g] = b[g];
        }
      } else {
#pragma unroll
        for (int g = 0; g < 4; g++) if (rbase + g < M) kb[(size_t)(rbase + g) * 256 + n] = f2bf(acc[nf][g] + bi);
      }
    } else if (MODE == 0) {
#pragma unroll
      for (int g = 0; g < 4; g++) if (rbase + g < M) ob[(size_t)(rbase + g) * 256 + n] = f2bf(acc[nf][g] + bi);
    } else {
#pragma unroll
      for (int g = 0; g < 4; g++) if (rbase + g < M) of[(size_t)(rbase + g) * 256 + n] = acc[nf][g] + bi;
    }
  }
}

// ---------------- flash attention: barrier-free, LDS-free, swapped QK^T ----------------
// grid (NSPLIT, B/64, H); 4 independent waves per WG, each owns 16 q-rows.
// scores^T = mfma(A=K, B=Q): lane(lr,lg) holds sc[nf][reg] = S[s = s0+nf*16+lg*4+reg][q = lr].
// softmax: per-lane over 16 regs + shfl_xor(16,32). P transposed to PV A-frag via bpermute.
__launch_bounds__(256)
__global__ void attn_k(const u16* __restrict__ qb, const u16* __restrict__ kb,
                       const u16* __restrict__ vt, const int* __restrict__ act,
                       float* __restrict__ pc, float* __restrict__ pml) {
  const int t = threadIdx.x;
  const int w = t >> 6, lane = t & 63, lr = lane & 15, lg = lane >> 4;
  const int si = blockIdx.x, bt = blockIdx.y, h = blockIdx.z;
  const int b0 = bt * 64;
  const int qrow = b0 + w * 16 + lr;
  const float SC = 0.125f * 1.44269504089f;   // (1/sqrt(64)) * log2(e) -> use exp2

  // Q B-fragments, loaded once (q = lr, k = kf*32 + lg*8 + e)
  bf16x8 qf0, qf1;
  {
    const u16* qp = qb + (size_t)qrow * 256 + h * 64 + lg * 8;
    qf0 = ld_frag(qp);
    qf1 = ld_frag(qp + 32);
  }
  const int* arow = act + (size_t)qrow * S_TOT;
  const u16* kbase = kb + h * 64 + (size_t)lr * 256 + lg * 8;
  const u16* vbase = vt + (size_t)(h * 64 + lr) * S_LD + lg * 8;

  f32x4 ctx[4] = {};
  float m = -3e38f, l = 0.f;

  for (int ci = si; ci < NCHUNK; ci += NSPLIT) {
    const int s0 = ci * 64;
    // ---- mask loads (16-aligned strips; S_TOT % 16 == 0 so never straddles) ----
    int4 mk[4];
#pragma unroll
    for (int nf = 0; nf < 4; nf++) {
      if (s0 + nf * 16 < S_TOT) mk[nf] = *(const int4*)(arow + s0 + nf * 16 + lg * 4);
      else                      mk[nf] = make_int4(0, 0, 0, 0);
    }
    // ---- QK^T swapped: A=K rows s, B=Q ----
    f32x4 sc[4] = {};
#pragma unroll
    for (int nf = 0; nf < 4; nf++) {
      int sb = s0 + nf * 16;
      const u16* kp = (sb < S_TOT) ? (kbase + (size_t)sb * 256) : (kbase + (size_t)(S_TOT - 16) * 256);
      bf16x8 k0 = ld_frag(kp);
      bf16x8 k1 = ld_frag(kp + 32);
      sc[nf] = __builtin_amdgcn_mfma_f32_16x16x32_bf16(k0, qf0, sc[nf], 0, 0, 0);
      sc[nf] = __builtin_amdgcn_mfma_f32_16x16x32_bf16(k1, qf1, sc[nf], 0, 0, 0);
    }
    // ---- mask + scale (scores now in log2 domain) ----
#pragma unroll
    for (int nf = 0; nf < 4; nf++) {
      sc[nf][0] = (mk[nf].x > 0) ? sc[nf][0] * SC : -1e9f;
      sc[nf][1] = (mk[nf].y > 0) ? sc[nf][1] * SC : -1e9f;
      sc[nf][2] = (mk[nf].z > 0) ? sc[nf][2] * SC : -1e9f;
      sc[nf][3] = (mk[nf].w > 0) ? sc[nf][3] * SC : -1e9f;
    }
    // ---- chunk max per q (lane-local 16 + 2 shfl) ----
    float mc = sc[0][0];
#pragma unroll
    for (int nf = 0; nf < 4; nf++)
#pragma unroll
      for (int reg = 0; reg < 4; reg++) mc = fmaxf(mc, sc[nf][reg]);
    mc = fmaxf(mc, __shfl_xor(mc, 16));
    mc = fmaxf(mc, __shfl_xor(mc, 32));
    // ---- defer-max: rescale only when running max actually grows ----
    if (!__all(mc <= m)) {
      float mn = fmaxf(m, mc);
      float al = exp2f(m - mn);
      m = mn;
      l *= al;
#pragma unroll
      for (int reg = 0; reg < 4; reg++) {
        float alr = __shfl(al, lg * 4 + reg);
#pragma unroll
        for (int nf = 0; nf < 4; nf++) ctx[nf][reg] *= alr;
      }
    }
    // ---- exp2 + sum ----
    float ls = 0.f;
#pragma unroll
    for (int nf = 0; nf < 4; nf++)
#pragma unroll
      for (int reg = 0; reg < 4; reg++) {
        float p = exp2f(sc[nf][reg] - m);
        sc[nf][reg] = p;
        ls += p;
      }
    ls += __shfl_xor(ls, 16);
    ls += __shfl_xor(ls, 32);
    l += ls;
    // ---- pack P to bf16 pairs: pk[nf][j] = P[s=nf*16+lg*4+2j .. +1][q=lr] ----
    uint_t pk[4][2];
#pragma unroll
    for (int nf = 0; nf < 4; nf++) {
      pk[nf][0] = cvtpk(sc[nf][0], sc[nf][1]);
      pk[nf][1] = cvtpk(sc[nf][2], sc[nf][3]);
    }
    // ---- PV: for each k-chunk c (32 s), build P A-frag via bpermute, mfma with V^T B-frags ----
#pragma unroll
    for (int c = 0; c < 2; c++) {
      uint_t d[4];
      const int blane = lr + ((lg & 1) << 5);
#pragma unroll
      for (int r = 0; r < 4; r++) {
        int sl = blane + ((r >> 1) << 4);
        uint_t t0 = __shfl(pk[2 * c][r & 1], sl);
        uint_t t1 = __shfl(pk[2 * c + 1][r & 1], sl);
        d[r] = (lg >= 2) ? t1 : t0;
      }
      uint4 du; du.x = d[0]; du.y = d[1]; du.z = d[2]; du.w = d[3];
      bf16x8 pa = __builtin_bit_cast(bf16x8, du);
#pragma unroll
      for (int df = 0; df < 4; df++) {
        bf16x8 vf = ld_frag(vbase + (size_t)(df * 16) * S_LD + s0 + c * 32);
        ctx[df] = __builtin_amdgcn_mfma_f32_16x16x32_bf16(pa, vf, ctx[df], 0, 0, 0);
      }
    }
  }
  // ---- write partials: ctx row q = lg*4+reg, col d = df*16+lr ----
#pragma unroll
  for (int df = 0; df < 4; df++)
#pragma unroll
    for (int reg = 0; reg < 4; reg++) {
      int b = b0 + 16 * w + lg * 4 + reg;
      int d = df * 16 + lr;
      pc[((((size_t)si * B_TOT + b) * NHEAD + h) << 6) + d] = ctx[df][reg];
    }
  if (lane < 16) {
    size_t base = (((size_t)si * B_TOT + qrow) * NHEAD + h) * 2;
    pml[base] = m;
    pml[base + 1] = l;
  }
}

// ---------------- combine split partials (m,l in log2 domain) ----------------
__global__ void combine_k(const float* __restrict__ pc, const float* __restrict__ pml,
                          const float* __restrict__ vm, u16* __restrict__ ctxb) {
  const int b = blockIdx.x, t = threadIdx.x;
  const int h = t >> 6, d = t & 63;
  float ms[NSPLIT], ls[NSPLIT];
  float M = -3e38f;
#pragma unroll
  for (int si = 0; si < NSPLIT; si++) {
    size_t base = (((size_t)si * B_TOT + b) * NHEAD + h) * 2;
    ms[si] = pml[base];
    ls[si] = pml[base + 1];
    M = fmaxf(M, ms[si]);
  }
  float L = 0.f, a = 0.f;
#pragma unroll
  for (int si = 0; si < NSPLIT; si++) {
    float wgt = exp2f(ms[si] - M);
    L += ls[si] * wgt;
    a += wgt * pc[((((size_t)si * B_TOT + b) * NHEAD + h) << 6) + d];
  }
  float r = (M < -1e8f) ? vm[t] : (a / L);
  ctxb[(size_t)b * 256 + t] = f2bf(r);
}

// ---------------- launch ----------------
extern "C" void kernel_launch(void* const* d_in, const int* in_sizes, int n_in,
                              void* d_out, int out_size, void* d_ws, size_t ws_size,
                              hipStream_t stream) {
  const int*   act = (const int*)d_in[0];
  const float* nc  = (const float*)d_in[1];
  const float* emb = (const float*)d_in[2];
  const float* ipw = (const float*)d_in[3];
  const float* ipb = (const float*)d_in[4];
  const float* opw = (const float*)d_in[5];
  const float* opb = (const float*)d_in[6];
  float* out = (float*)d_out;
  char* ws = (char*)d_ws;

  size_t off = 0;
  auto alloc = [&](size_t bytes) { size_t r0 = off; off = (off + bytes + 255) & ~(size_t)255; return r0; };
  u16*   wqkv = (u16*)(ws + alloc(768 * 256 * 2));
  u16*   wout = (u16*)(ws + alloc(256 * 256 * 2));
  u16*   ncb  = (u16*)(ws + alloc((size_t)B_TOT * 256 * 2));
  u16*   embb = (u16*)(ws + alloc((size_t)S_TOT * 256 * 2));
  u16*   qb   = (u16*)(ws + alloc((size_t)B_TOT * 256 * 2));
  u16*   kbuf = (u16*)(ws + alloc((size_t)S_TOT * 256 * 2));
  u16*   vtb  = (u16*)(ws + alloc((size_t)256 * S_LD * 2));
  float* cmp  = (float*)(ws + alloc(80 * 256 * 4));
  float* vm   = (float*)(ws + alloc(256 * 4));
  float* pc   = (float*)(ws + alloc((size_t)NSPLIT * B_TOT * NHEAD * 64 * 4));
  float* pml  = (float*)(ws + alloc((size_t)NSPLIT * B_TOT * NHEAD * 2 * 4));
  u16*   ctxb = (u16*)(ws + alloc((size_t)B_TOT * 256 * 2));

  convert_all<<<2048, 256, 0, stream>>>(ipw, opw, nc, wqkv, wout, ncb);
  convert_emb<<<5000, 256, 0, stream>>>(emb, embb);
  zero_vt_pad<<<32, 256, 0, stream>>>(vtb);
  colmean_part<<<80, 256, 0, stream>>>(emb, cmp);
  vmean_k<<<1, 256, 0, stream>>>(cmp, ipw, ipb, vm);
  // q projection: rows 0..255 of in_proj
  gemm_bt<0><<<dim3(16, 4), 256, 0, stream>>>(ncb, wqkv, ipb, B_TOT, qb, nullptr, nullptr, nullptr);
  // kv projection: rows 256..767 of in_proj; N=512 (K cols 0..255, V cols 256..511)
  gemm_bt<1><<<dim3(313, 8), 256, 0, stream>>>(embb, wqkv + 256 * 256, ipb + 256, S_TOT,
                                               nullptr, kbuf, vtb, nullptr);
  attn_k<<<dim3(NSPLIT, 16, 4), 256, 0, stream>>>(qb, kbuf, vtb, act, pc, pml);
  combine_k<<<B_TOT, 256, 0, stream>>>(pc, pml, vm, ctxb);
  gemm_bt<2><<<dim3(16, 4), 256, 0, stream>>>(ctxb, wout, opb, B_TOT, nullptr, nullptr, nullptr, out);
}

// Round 4
// 200.045 us; speedup vs baseline: 1.5390x; 1.5390x over previous
//
#include <hip/hip_runtime.h>

typedef unsigned int uint_t;
typedef unsigned short u16;
typedef __attribute__((ext_vector_type(4))) float f32x4;
typedef __attribute__((ext_vector_type(16))) float f32x16;
typedef __attribute__((ext_vector_type(8))) __bf16 bf16x8;
typedef __attribute__((ext_vector_type(4))) __bf16 bf16x4;

#define S_TOT 20000
#define S_LD  20032   // padded V^T row stride
#define B_TOT 1024
#define NHEAD 4
#define NSPLIT 32
#define NCHUNK 313    // ceil(20000/64)

__device__ __forceinline__ u16 f2bf(float x) {
  uint_t u = __builtin_bit_cast(uint_t, x);
  u += 0x7FFFu + ((u >> 16) & 1u);
  return (u16)(u >> 16);
}

__device__ __forceinline__ uint_t cvtpk(float lo, float hi) {
  uint_t r;
  asm("v_cvt_pk_bf16_f32 %0, %1, %2" : "=v"(r) : "v"(lo), "v"(hi));
  return r;
}

__device__ __forceinline__ float bflo(uint_t u) { return __builtin_bit_cast(float, u << 16); }
__device__ __forceinline__ float bfhi(uint_t u) { return __builtin_bit_cast(float, u & 0xffff0000u); }

__device__ __forceinline__ bf16x8 ld_frag(const u16* p) {
  return __builtin_bit_cast(bf16x8, *(const uint4*)p);
}

__device__ __forceinline__ void gload_lds16(const void* g, void* l) {
  __builtin_amdgcn_global_load_lds((const __attribute__((address_space(1))) unsigned int*)g,
                                   (__attribute__((address_space(3))) unsigned int*)l, 16, 0, 0);
}

__device__ __forceinline__ f32x16 mfma_32x32x8(bf16x4 a, bf16x4 b, f32x16 c) {
  asm("v_mfma_f32_32x32x8_bf16 %0, %1, %2, %0" : "+v"(c) : "v"(a), "v"(b));
  return c;
}

// ---------------- conversions f32 -> bf16 ----------------
__global__ void convert_all(const float* __restrict__ ipw, const float* __restrict__ opw,
                            const float* __restrict__ nc,
                            u16* __restrict__ wqkv, u16* __restrict__ wout, u16* __restrict__ ncb) {
  int i = blockIdx.x * 256 + threadIdx.x;           // 0..524287
  if (i < 196608)      wqkv[i] = f2bf(ipw[i]);
  else if (i < 262144) wout[i - 196608] = f2bf(opw[i - 196608]);
  else                 ncb[i - 262144] = f2bf(nc[i - 262144]);
}

__global__ void convert_emb(const float* __restrict__ emb, u16* __restrict__ embb) {
  size_t i = (size_t)(blockIdx.x * 256 + threadIdx.x) * 4;   // 5000*256*4 = 5.12M
  float4 v = *(const float4*)(emb + i);
  uint2 o;
  o.x = f2bf(v.x) | ((uint_t)f2bf(v.y) << 16);
  o.y = f2bf(v.z) | ((uint_t)f2bf(v.w) << 16);
  *(uint2*)(embb + i) = o;
}

// zero the padded tail columns of V^T (s in [20000,20032))
__global__ void zero_vt_pad(u16* __restrict__ vt) {
  int i = blockIdx.x * 256 + threadIdx.x;           // 8192 = 256 rows * 32
  int d = i >> 5, j = i & 31;
  vt[(size_t)d * S_LD + S_TOT + j] = 0;
}

// ---------------- column mean of embed (deterministic 2-stage) ----------------
__global__ void colmean_part(const float* __restrict__ emb, float* __restrict__ cmp) {
  int t = threadIdx.x, p = blockIdx.x;              // 80 blocks x 250 rows
  float s = 0.f;
  for (int r = p * 250; r < (p + 1) * 250; r++) s += emb[(size_t)r * 256 + t];
  cmp[p * 256 + t] = s;
}

__global__ void vmean_k(const float* __restrict__ cmp, const float* __restrict__ ipw,
                        const float* __restrict__ ipb, float* __restrict__ vm) {
  __shared__ float sm[256];
  int t = threadIdx.x;
  float s = 0.f;
  for (int p = 0; p < 80; p++) s += cmp[p * 256 + t];
  sm[t] = s * (1.0f / 20000.0f);
  __syncthreads();
  float acc = ipb[512 + t];
  const float* wv = ipw + (size_t)(512 + t) * 256;
  for (int c = 0; c < 256; c++) acc += sm[c] * wv[c];
  vm[t] = acc;
}

// ---------------- generic B^T GEMM: C[M x N] = A_bf16[M x 256] @ W_bf16[N x 256]^T + bias ----
template<int MODE>
__launch_bounds__(256)
__global__ void gemm_bt(const u16* __restrict__ A, const u16* __restrict__ W,
                        const float* __restrict__ bias, int M,
                        u16* __restrict__ ob, u16* __restrict__ kb,
                        u16* __restrict__ vtb, float* __restrict__ of) {
  __shared__ __align__(16) u16 sA[64][40];
  __shared__ __align__(16) u16 sW[64][40];
  const int t = threadIdx.x;
  const int w = t >> 6, lane = t & 63, lr = lane & 15, lg = lane >> 4;
  const int m0 = blockIdx.x * 64, n0 = blockIdx.y * 64;
  const int r = t >> 2, kc = (t & 3) * 8;
  f32x4 acc[4] = {};
  int ga = m0 + r; if (ga > M - 1) ga = M - 1;
  const u16* ap = A + (size_t)ga * 256;
  const u16* wp = W + (size_t)(n0 + r) * 256;
  for (int k0 = 0; k0 < 256; k0 += 32) {
    *(uint4*)&sA[r][kc] = *(const uint4*)(ap + k0 + kc);
    *(uint4*)&sW[r][kc] = *(const uint4*)(wp + k0 + kc);
    __syncthreads();
    bf16x8 af = ld_frag(&sA[16 * w + lr][lg * 8]);
#pragma unroll
    for (int nf = 0; nf < 4; nf++) {
      bf16x8 bfr = ld_frag(&sW[16 * nf + lr][lg * 8]);
      acc[nf] = __builtin_amdgcn_mfma_f32_16x16x32_bf16(af, bfr, acc[nf], 0, 0, 0);
    }
    __syncthreads();
  }
  const int rbase = m0 + 16 * w + lg * 4;
#pragma unroll
  for (int nf = 0; nf < 4; nf++) {
    const int n = n0 + nf * 16 + lr;
    const float bi = bias[n];
    if (MODE == 1) {
      if (n >= 256) {
        const int vr = n - 256;
        u16 b[4];
#pragma unroll
        for (int g = 0; g < 4; g++) b[g] = f2bf(acc[nf][g] + bi);
        if (rbase + 3 < M) {
          uint2 p2; p2.x = b[0] | ((uint_t)b[1] << 16); p2.y = b[2] | ((uint_t)b[3] << 16);
          *(uint2*)&vtb[(size_t)vr * S_LD + rbase] = p2;
        } else {
#pragma unroll
          for (int g = 0; g < 4; g++) if (rbase + g < M) vtb[(size_t)vr * S_LD + rbase + g] = b[g];
        }
      } else {
#pragma unroll
        for (int g = 0; g < 4; g++) if (rbase + g < M) kb[(size_t)(rbase + g) * 256 + n] = f2bf(acc[nf][g] + bi);
      }
    } else if (MODE == 0) {
#pragma unroll
      for (int g = 0; g < 4; g++) if (rbase + g < M) ob[(size_t)(rbase + g) * 256 + n] = f2bf(acc[nf][g] + bi);
    } else {
#pragma unroll
      for (int g = 0; g < 4; g++) if (rbase + g < M) of[(size_t)(rbase + g) * 256 + n] = acc[nf][g] + bi;
    }
  }
}

// ---------------- flash attention: 32x32 MFMA, LDS double-buffer, swapped QK^T ----------------
// grid (NSPLIT, B/128, H); 4 waves per WG, wave w owns q-rows b0+w*32..+31.
// QK^T: D[s][q] via mfma_32x32x16(A=K, B=Q): lane(q5,hi) holds sc[b][r] =
//   S[s = b*32 + (r&3) + 8*(r>>2) + 4*hi][q = q5]  -> softmax lane-local + 1 shfl_xor(32).
// PV: mfma_32x32x8(A=V^T, B=P) consumes P regs directly (k = hi*4+e matches reg layout).
__launch_bounds__(256, 4)
__global__ void attn_k(const u16* __restrict__ qb, const u16* __restrict__ kb,
                       const u16* __restrict__ vt, const int* __restrict__ act,
                       float* __restrict__ pc, float* __restrict__ pml) {
  __shared__ __align__(16) u16 sK[2][64][64];
  __shared__ __align__(16) u16 sV[2][64][64];
  const int t = threadIdx.x;
  const int w = t >> 6, lane = t & 63;
  const int q5 = lane & 31, hi = lane >> 5;
  const int si = blockIdx.x, bt = blockIdx.y, h = blockIdx.z;
  const int b0 = bt * 128;
  const int qrow = b0 + w * 32 + q5;
  const float SC = 0.125f * 1.44269504089f;   // (1/sqrt(64)) * log2(e)

  // Q B-fragments (loaded once): B[k][n]: n=q5, k = kc*16 + hi*8 + e
  bf16x8 qf[4];
#pragma unroll
  for (int kc = 0; kc < 4; kc++)
    qf[kc] = ld_frag(qb + (size_t)qrow * 256 + h * 64 + kc * 16 + hi * 8);
  const int* arow = act + (size_t)qrow * S_TOT;

  f32x16 ctx[2] = {{}, {}};
  float m = -3e38f, l = 0.f;

  // stage: K tile [64 s][64 k] and V^T tile [64 d][64 s], XOR-swizzled source -> linear LDS
  auto stage = [&](int buf, int s0) {
#pragma unroll
    for (int j = 0; j < 2; j++) {
      const int rg = w * 16 + j * 8 + (lane >> 3);
      const int c16 = (lane & 7) ^ ((lane >> 3) & 7);
      int srow = s0 + rg; if (srow > S_TOT - 1) srow = S_TOT - 1;
      gload_lds16(kb + (size_t)srow * 256 + h * 64 + c16 * 8, &sK[buf][w * 16 + j * 8][0]);
      gload_lds16(vt + (size_t)(h * 64 + rg) * S_LD + s0 + c16 * 8, &sV[buf][w * 16 + j * 8][0]);
    }
  };

  stage(0, si * 64);
  __syncthreads();
  int cur = 0;

  for (int ci = si; ci < NCHUNK; ci += NSPLIT) {
    const int s0c = ci * 64;
    if (ci + NSPLIT < NCHUNK) stage(cur ^ 1, (ci + NSPLIT) * 64);

    // ---- mask loads: int4 covers s = sb..sb+3 for q=q5 ----
    int4 mk[2][4];
#pragma unroll
    for (int b = 0; b < 2; b++)
#pragma unroll
      for (int j = 0; j < 4; j++) {
        int sb = s0c + b * 32 + 8 * j + 4 * hi;
        mk[b][j] = (sb < S_TOT) ? *(const int4*)(arow + sb) : make_int4(0, 0, 0, 0);
      }
    // ---- QK^T ----
    f32x16 sc[2] = {{}, {}};
#pragma unroll
    for (int kc = 0; kc < 4; kc++) {
      const int slot = ((2 * kc + hi) ^ (q5 & 7)) * 8;
      bf16x8 ka0 = ld_frag(&sK[cur][q5][slot]);
      bf16x8 ka1 = ld_frag(&sK[cur][32 + q5][slot]);
      sc[0] = __builtin_amdgcn_mfma_f32_32x32x16_bf16(ka0, qf[kc], sc[0], 0, 0, 0);
      sc[1] = __builtin_amdgcn_mfma_f32_32x32x16_bf16(ka1, qf[kc], sc[1], 0, 0, 0);
    }
    // ---- mask + scale (log2 domain) ----
#pragma unroll
    for (int b = 0; b < 2; b++)
#pragma unroll
      for (int r = 0; r < 16; r++) {
        int mv = (r & 3) == 0 ? mk[b][r >> 2].x : (r & 3) == 1 ? mk[b][r >> 2].y
               : (r & 3) == 2 ? mk[b][r >> 2].z : mk[b][r >> 2].w;
        float v = sc[b][r] * SC;
        sc[b][r] = (mv > 0) ? v : -1e9f;
      }
    // ---- chunk max (lane-local 32 + 1 shfl) ----
    float mc = sc[0][0];
#pragma unroll
    for (int b = 0; b < 2; b++)
#pragma unroll
      for (int r = 0; r < 16; r++) mc = fmaxf(mc, sc[b][r]);
    mc = fmaxf(mc, __shfl_xor(mc, 32));
    // ---- rescale whenever running max grows (THR=0: P stays <= 1) ----
    if (!__all(mc <= m)) {
      float mn = fmaxf(m, mc);
      float al = exp2f(m - mn);
      m = mn;
      l *= al;
#pragma unroll
      for (int dc = 0; dc < 2; dc++)
#pragma unroll
        for (int r = 0; r < 16; r++) ctx[dc][r] *= al;   // ctx cols = q = q5: lane-local
    }
    // ---- exp2 + pack to bf16; denominator from the ROUNDED values (consistency) ----
    uint2 pk[2][4];
    float ls = 0.f;
#pragma unroll
    for (int b = 0; b < 2; b++)
#pragma unroll
      for (int j = 0; j < 4; j++) {
        float p0 = exp2f(sc[b][4 * j + 0] - m);
        float p1 = exp2f(sc[b][4 * j + 1] - m);
        float p2 = exp2f(sc[b][4 * j + 2] - m);
        float p3 = exp2f(sc[b][4 * j + 3] - m);
        pk[b][j].x = cvtpk(p0, p1);
        pk[b][j].y = cvtpk(p2, p3);
        ls += (bflo(pk[b][j].x) + bfhi(pk[b][j].x)) + (bflo(pk[b][j].y) + bfhi(pk[b][j].y));
      }
    ls += __shfl_xor(ls, 32);
    l += ls;
    // ---- PV: B-frag = P regs (k = hi*4+e), A-frag = V^T b64 reads ----
#pragma unroll
    for (int b = 0; b < 2; b++)
#pragma unroll
      for (int j = 0; j < 4; j++) {
        bf16x4 pb = __builtin_bit_cast(bf16x4, pk[b][j]);
        const int slot = ((4 * b + j) ^ (q5 & 7)) * 8 + hi * 4;
        bf16x4 va0 = *(const bf16x4*)&sV[cur][q5][slot];
        bf16x4 va1 = *(const bf16x4*)&sV[cur][32 + q5][slot];
        ctx[0] = mfma_32x32x8(va0, pb, ctx[0]);
        ctx[1] = mfma_32x32x8(va1, pb, ctx[1]);
      }
    __syncthreads();
    cur ^= 1;
  }
  // ---- write partials: ctx[dc][reg]: d = dc*32 + (reg&3) + 8*(reg>>2) + 4*hi, q = q5 ----
  size_t obase = (((size_t)si * B_TOT + qrow) * NHEAD + h) * 64;
#pragma unroll
  for (int dc = 0; dc < 2; dc++)
#pragma unroll
    for (int r = 0; r < 16; r++) {
      int d = dc * 32 + (r & 3) + 8 * (r >> 2) + 4 * hi;
      pc[obase + d] = ctx[dc][r];
    }
  if (lane < 32) {
    size_t base = (((size_t)si * B_TOT + qrow) * NHEAD + h) * 2;
    pml[base] = m;
    pml[base + 1] = l;
  }
}

// ---------------- combine split partials (m,l in log2 domain) ----------------
__global__ void combine_k(const float* __restrict__ pc, const float* __restrict__ pml,
                          const float* __restrict__ vm, u16* __restrict__ ctxb) {
  const int b = blockIdx.x, t = threadIdx.x;
  const int h = t >> 6, d = t & 63;
  float ms[NSPLIT], ls[NSPLIT];
  float M = -3e38f;
#pragma unroll
  for (int si = 0; si < NSPLIT; si++) {
    size_t base = (((size_t)si * B_TOT + b) * NHEAD + h) * 2;
    ms[si] = pml[base];
    ls[si] = pml[base + 1];
    M = fmaxf(M, ms[si]);
  }
  float L = 0.f, a = 0.f;
#pragma unroll
  for (int si = 0; si < NSPLIT; si++) {
    float wgt = exp2f(ms[si] - M);
    L += ls[si] * wgt;
    a += wgt * pc[((((size_t)si * B_TOT + b) * NHEAD + h) << 6) + d];
  }
  float r = (M < -1e8f) ? vm[t] : (a / L);
  ctxb[(size_t)b * 256 + t] = f2bf(r);
}

// ---------------- launch ----------------
extern "C" void kernel_launch(void* const* d_in, const int* in_sizes, int n_in,
                              void* d_out, int out_size, void* d_ws, size_t ws_size,
                              hipStream_t stream) {
  const int*   act = (const int*)d_in[0];
  const float* nc  = (const float*)d_in[1];
  const float* emb = (const float*)d_in[2];
  const float* ipw = (const float*)d_in[3];
  const float* ipb = (const float*)d_in[4];
  const float* opw = (const float*)d_in[5];
  const float* opb = (const float*)d_in[6];
  float* out = (float*)d_out;
  char* ws = (char*)d_ws;

  size_t off = 0;
  auto alloc = [&](size_t bytes) { size_t r0 = off; off = (off + bytes + 255) & ~(size_t)255; return r0; };
  u16*   wqkv = (u16*)(ws + alloc(768 * 256 * 2));
  u16*   wout = (u16*)(ws + alloc(256 * 256 * 2));
  u16*   ncb  = (u16*)(ws + alloc((size_t)B_TOT * 256 * 2));
  u16*   qb   = (u16*)(ws + alloc((size_t)B_TOT * 256 * 2));
  u16*   kbuf = (u16*)(ws + alloc((size_t)S_TOT * 256 * 2));
  u16*   vtb  = (u16*)(ws + alloc((size_t)256 * S_LD * 2));
  float* cmp  = (float*)(ws + alloc(80 * 256 * 4));
  float* vm   = (float*)(ws + alloc(256 * 4));
  float* pml  = (float*)(ws + alloc((size_t)NSPLIT * B_TOT * NHEAD * 2 * 4));
  u16*   ctxb = (u16*)(ws + alloc((size_t)B_TOT * 256 * 2));
  // union region: embb (10.25 MB, dead after kv-projection) overlaid by pc (32 MB)
  size_t ubase = off;
  u16*   embb = (u16*)(ws + ubase);
  float* pc   = (float*)(ws + ubase);

  convert_all<<<2048, 256, 0, stream>>>(ipw, opw, nc, wqkv, wout, ncb);
  convert_emb<<<5000, 256, 0, stream>>>(emb, embb);
  zero_vt_pad<<<32, 256, 0, stream>>>(vtb);
  colmean_part<<<80, 256, 0, stream>>>(emb, cmp);
  vmean_k<<<1, 256, 0, stream>>>(cmp, ipw, ipb, vm);
  // q projection: rows 0..255 of in_proj
  gemm_bt<0><<<dim3(16, 4), 256, 0, stream>>>(ncb, wqkv, ipb, B_TOT, qb, nullptr, nullptr, nullptr);
  // kv projection: rows 256..767 of in_proj; N=512 (K cols 0..255, V cols 256..511)
  gemm_bt<1><<<dim3(313, 8), 256, 0, stream>>>(embb, wqkv + 256 * 256, ipb + 256, S_TOT,
                                               nullptr, kbuf, vtb, nullptr);
  attn_k<<<dim3(NSPLIT, B_TOT / 128, NHEAD), 256, 0, stream>>>(qb, kbuf, vtb, act, pc, pml);
  combine_k<<<B_TOT, 256, 0, stream>>>(pc, pml, vm, ctxb);
  gemm_bt<2><<<dim3(16, 4), 256, 0, stream>>>(ctxb, wout, opb, B_TOT, nullptr, nullptr, nullptr, out);
}

// Round 5
// 154.971 us; speedup vs baseline: 1.9866x; 1.2908x over previous
//
#include <hip/hip_runtime.h>

typedef unsigned int uint_t;
typedef unsigned short u16;
typedef __attribute__((ext_vector_type(4))) float f32x4;
typedef __attribute__((ext_vector_type(16))) float f32x16;
typedef __attribute__((ext_vector_type(8))) __bf16 bf16x8;
typedef __attribute__((ext_vector_type(4))) __bf16 bf16x4;

#define S_TOT 20000
#define S_LD  20032   // padded V^T row stride
#define B_TOT 1024
#define NHEAD 4
#define NSPLIT 32
#define NCHUNK 313    // ceil(20000/64)

__device__ __forceinline__ u16 f2bf(float x) {
  uint_t u = __builtin_bit_cast(uint_t, x);
  u += 0x7FFFu + ((u >> 16) & 1u);
  return (u16)(u >> 16);
}

__device__ __forceinline__ uint_t cvtpk(float lo, float hi) {
  uint_t r;
  asm("v_cvt_pk_bf16_f32 %0, %1, %2" : "=v"(r) : "v"(lo), "v"(hi));
  return r;
}

__device__ __forceinline__ bf16x8 ld_frag(const u16* p) {
  return __builtin_bit_cast(bf16x8, *(const uint4*)p);
}

__device__ __forceinline__ void gload_lds16(const void* g, void* l) {
  __builtin_amdgcn_global_load_lds((const __attribute__((address_space(1))) unsigned int*)g,
                                   (__attribute__((address_space(3))) unsigned int*)l, 16, 0, 0);
}

__device__ __forceinline__ f32x16 mfma_32x32x8(bf16x4 a, bf16x4 b, f32x16 c) {
  asm("v_mfma_f32_32x32x8_bf16 %0, %1, %2, %0" : "+v"(c) : "v"(a), "v"(b));
  return c;
}

// ---------------- conversions f32 -> bf16 (weights, neural_context) ----------------
__global__ void convert_all(const float* __restrict__ ipw, const float* __restrict__ opw,
                            const float* __restrict__ nc,
                            u16* __restrict__ wqkv, u16* __restrict__ wout, u16* __restrict__ ncb) {
  int i = blockIdx.x * 256 + threadIdx.x;           // 0..524287
  if (i < 196608)      wqkv[i] = f2bf(ipw[i]);
  else if (i < 262144) wout[i - 196608] = f2bf(opw[i - 196608]);
  else                 ncb[i - 262144] = f2bf(nc[i - 262144]);
}

// ---------------- fused: emb f32->bf16 convert + column partial sums ----------------
// 200 blocks x 256 threads; block p handles rows p*100..p*100+99.
__global__ void conv_cm(const float* __restrict__ emb, u16* __restrict__ embb,
                        float* __restrict__ cmp) {
  __shared__ float4 rbuf[256];
  const int t = threadIdx.x, p = blockIdx.x;
  const int c4 = (t & 63) * 4, rg = t >> 6;
  float s0 = 0.f, s1 = 0.f, s2 = 0.f, s3 = 0.f;
#pragma unroll 4
  for (int i = 0; i < 25; i++) {
    int r = p * 100 + rg + i * 4;
    float4 v = *(const float4*)(emb + (size_t)r * 256 + c4);
    uint2 o;
    o.x = f2bf(v.x) | ((uint_t)f2bf(v.y) << 16);
    o.y = f2bf(v.z) | ((uint_t)f2bf(v.w) << 16);
    *(uint2*)(embb + (size_t)r * 256 + c4) = o;
    s0 += v.x; s1 += v.y; s2 += v.z; s3 += v.w;
  }
  rbuf[t] = make_float4(s0, s1, s2, s3);
  __syncthreads();
  if (t < 64) {
    float4 a = rbuf[t], b = rbuf[t + 64], c = rbuf[t + 128], d = rbuf[t + 192];
    float4 o = make_float4(a.x + b.x + c.x + d.x, a.y + b.y + c.y + d.y,
                           a.z + b.z + c.z + d.z, a.w + b.w + c.w + d.w);
    *(float4*)(cmp + p * 256 + t * 4) = o;
  }
}

// zero the padded tail columns of V^T (s in [20000,20032))
__global__ void zero_vt_pad(u16* __restrict__ vt) {
  int i = blockIdx.x * 256 + threadIdx.x;           // 8192 = 256 rows * 32
  int d = i >> 5, j = i & 31;
  vt[(size_t)d * S_LD + S_TOT + j] = 0;
}

// ---------------- mask bit-pack: pmT[ci][row] = 64 bits for s = ci*64..+63 ----------------
__global__ void pack_k(const int* __restrict__ act, uint_t* __restrict__ pmT) {
  int gw = (blockIdx.x * 256 + threadIdx.x) >> 6;
  int lane = threadIdx.x & 63;
  int row = gw / NCHUNK, ci = gw - row * NCHUNK;
  if (row >= B_TOT) return;
  int s = ci * 64 + lane;
  int v = (s < S_TOT) ? act[(size_t)row * S_TOT + s] : 0;
  unsigned long long b = __ballot(v > 0);
  if (lane == 0) {
    uint2 o; o.x = (uint_t)b; o.y = (uint_t)(b >> 32);
    *(uint2*)(pmT + ((size_t)ci * B_TOT + row) * 2) = o;
  }
}

// ---------------- v_mean = (mean_emb @ Wv^T + bv), parallel ----------------
__global__ void vmean2_k(const float* __restrict__ cmp, const float* __restrict__ ipw,
                         const float* __restrict__ ipb, float* __restrict__ vm) {
  __shared__ float mean[256];
  __shared__ float red[256];
  const int t = threadIdx.x;
  float s = 0.f;
#pragma unroll 8
  for (int p = 0; p < 200; p++) s += cmp[p * 256 + t];
  mean[t] = s * (1.0f / 20000.0f);
  __syncthreads();
  const int row = blockIdx.x * 16 + (t >> 4), l16 = t & 15;
  const float* wv = ipw + (size_t)(512 + row) * 256 + l16 * 16;
  float a = 0.f;
#pragma unroll
  for (int j = 0; j < 16; j++) a += mean[l16 * 16 + j] * wv[j];
  red[t] = a;
  __syncthreads();
  if (l16 == 0) {
    float s2 = 0.f;
#pragma unroll
    for (int j = 0; j < 16; j++) s2 += red[t + j];
    vm[row] = s2 + ipb[512 + row];
  }
}

// ---------------- small B^T GEMM (q-proj, out-proj): C[M x 256] ----------------
template<int MODE>   // 0: out bf16, 2: out f32
__launch_bounds__(256)
__global__ void gemm_bt(const u16* __restrict__ A, const u16* __restrict__ W,
                        const float* __restrict__ bias, int M,
                        u16* __restrict__ ob, float* __restrict__ of) {
  __shared__ __align__(16) u16 sA[64][40];
  __shared__ __align__(16) u16 sW[64][40];
  const int t = threadIdx.x;
  const int w = t >> 6, lane = t & 63, lr = lane & 15, lg = lane >> 4;
  const int m0 = blockIdx.x * 64, n0 = blockIdx.y * 64;
  const int r = t >> 2, kc = (t & 3) * 8;
  f32x4 acc[4] = {};
  int ga = m0 + r; if (ga > M - 1) ga = M - 1;
  const u16* ap = A + (size_t)ga * 256;
  const u16* wp = W + (size_t)(n0 + r) * 256;
  for (int k0 = 0; k0 < 256; k0 += 32) {
    *(uint4*)&sA[r][kc] = *(const uint4*)(ap + k0 + kc);
    *(uint4*)&sW[r][kc] = *(const uint4*)(wp + k0 + kc);
    __syncthreads();
    bf16x8 af = ld_frag(&sA[16 * w + lr][lg * 8]);
#pragma unroll
    for (int nf = 0; nf < 4; nf++) {
      bf16x8 bfr = ld_frag(&sW[16 * nf + lr][lg * 8]);
      acc[nf] = __builtin_amdgcn_mfma_f32_16x16x32_bf16(af, bfr, acc[nf], 0, 0, 0);
    }
    __syncthreads();
  }
  const int rbase = m0 + 16 * w + lg * 4;
#pragma unroll
  for (int nf = 0; nf < 4; nf++) {
    const int n = n0 + nf * 16 + lr;
    const float bi = bias[n];
    if (MODE == 0) {
#pragma unroll
      for (int g = 0; g < 4; g++) if (rbase + g < M) ob[(size_t)(rbase + g) * 256 + n] = f2bf(acc[nf][g] + bi);
    } else {
#pragma unroll
      for (int g = 0; g < 4; g++) if (rbase + g < M) of[(size_t)(rbase + g) * 256 + n] = acc[nf][g] + bi;
    }
  }
}

// ---------------- KV projection: C[20000 x 512] = embb @ Wkv^T + b ----------------
// 128x64 tile, BK=64, gload_lds + XOR-swizzled source, double-buffered, 1 barrier/K-step.
// n<256 -> K[m][n]; n>=256 -> V^T[n-256][m].
__launch_bounds__(256, 3)
__global__ void gemm_kv(const u16* __restrict__ A, const u16* __restrict__ W,
                        const float* __restrict__ bias,
                        u16* __restrict__ kb, u16* __restrict__ vtb) {
  __shared__ __align__(16) u16 sA[2][128][64];
  __shared__ __align__(16) u16 sW[2][64][64];
  const int t = threadIdx.x, w = t >> 6, lane = t & 63;
  const int q5 = lane & 31, hi = lane >> 5;
  const int wr = w >> 1, wc = w & 1;
  const int m0 = blockIdx.x * 128, n0 = blockIdx.y * 64;

  auto stage = [&](int buf, int k0) {
#pragma unroll
    for (int j = 0; j < 4; j++) {           // A: 1024 16B-chunks
      int c = j * 256 + w * 64 + lane;
      int row = c >> 3, slot = c & 7;
      int gm = m0 + row; if (gm > S_TOT - 1) gm = S_TOT - 1;
      gload_lds16(A + (size_t)gm * 256 + k0 + ((slot ^ (row & 7)) * 8),
                  &sA[buf][0][0] + (size_t)(j * 256 + w * 64) * 8);
    }
#pragma unroll
    for (int j = 0; j < 2; j++) {           // W: 512 16B-chunks
      int c = j * 256 + w * 64 + lane;
      int row = c >> 3, slot = c & 7;
      gload_lds16(W + (size_t)(n0 + row) * 256 + k0 + ((slot ^ (row & 7)) * 8),
                  &sW[buf][0][0] + (size_t)(j * 256 + w * 64) * 8);
    }
  };

  f32x16 acc[2] = {{}, {}};
  stage(0, 0);
  __syncthreads();
  for (int ks = 0; ks < 4; ks++) {
    const int buf = ks & 1;
    if (ks < 3) stage(buf ^ 1, (ks + 1) * 64);
#pragma unroll
    for (int k4 = 0; k4 < 4; k4++) {
      const int rowW = wc * 32 + q5;
      bf16x8 wf = ld_frag(&sW[buf][rowW][((2 * k4 + hi) ^ (rowW & 7)) * 8]);
#pragma unroll
      for (int blk = 0; blk < 2; blk++) {
        const int rowA = wr * 64 + blk * 32 + q5;
        bf16x8 af = ld_frag(&sA[buf][rowA][((2 * k4 + hi) ^ (rowA & 7)) * 8]);
        acc[blk] = __builtin_amdgcn_mfma_f32_32x32x16_bf16(af, wf, acc[blk], 0, 0, 0);
      }
    }
    __syncthreads();
  }
  const int n = n0 + wc * 32 + q5;
  const float bi = bias[n];
  if (n < 256) {
#pragma unroll
    for (int blk = 0; blk < 2; blk++)
#pragma unroll
      for (int r = 0; r < 16; r++) {
        int mrow = m0 + wr * 64 + blk * 32 + (r & 3) + 8 * (r >> 2) + 4 * hi;
        if (mrow < S_TOT) kb[(size_t)mrow * 256 + n] = f2bf(acc[blk][r] + bi);
      }
  } else {
    const int vr = n - 256;
#pragma unroll
    for (int blk = 0; blk < 2; blk++)
#pragma unroll
      for (int g = 0; g < 4; g++) {
        int mb = m0 + wr * 64 + blk * 32 + 8 * g + 4 * hi;
        u16 b4[4];
#pragma unroll
        for (int j = 0; j < 4; j++) b4[j] = f2bf(acc[blk][4 * g + j] + bi);
        if (mb + 3 < S_TOT) {
          uint2 p2; p2.x = b4[0] | ((uint_t)b4[1] << 16); p2.y = b4[2] | ((uint_t)b4[3] << 16);
          *(uint2*)&vtb[(size_t)vr * S_LD + mb] = p2;
        } else {
#pragma unroll
          for (int j = 0; j < 4; j++) if (mb + j < S_TOT) vtb[(size_t)vr * S_LD + mb + j] = b4[j];
        }
      }
  }
}

// ---------------- flash attention: 32x32 MFMA, LDS dbuf, swapped QK^T, bitmask ----------------
__launch_bounds__(256, 4)
__global__ void attn_k(const u16* __restrict__ qb, const u16* __restrict__ kb,
                       const u16* __restrict__ vt, const uint_t* __restrict__ pmT,
                       float* __restrict__ pc, float* __restrict__ pml) {
  __shared__ __align__(16) u16 sK[2][64][64];
  __shared__ __align__(16) u16 sV[2][64][64];
  const int t = threadIdx.x;
  const int w = t >> 6, lane = t & 63;
  const int q5 = lane & 31, hi = lane >> 5;
  const int si = blockIdx.x, bt = blockIdx.y, h = blockIdx.z;
  const int b0 = bt * 128;
  const int qrow = b0 + w * 32 + q5;
  const float SC = 0.125f * 1.44269504089f;   // (1/sqrt(64)) * log2(e)

  // Q B-fragments (loaded once): n=q5, k = kc*16 + hi*8 + e
  bf16x8 qf[4];
#pragma unroll
  for (int kc = 0; kc < 4; kc++)
    qf[kc] = ld_frag(qb + (size_t)qrow * 256 + h * 64 + kc * 16 + hi * 8);

  f32x16 ctx[2] = {{}, {}};
  float m = -3e38f, l = 0.f;

  auto stage = [&](int buf, int s0) {
#pragma unroll
    for (int j = 0; j < 2; j++) {
      const int rg = w * 16 + j * 8 + (lane >> 3);
      const int c16 = (lane & 7) ^ ((lane >> 3) & 7);
      int srow = s0 + rg; if (srow > S_TOT - 1) srow = S_TOT - 1;
      gload_lds16(kb + (size_t)srow * 256 + h * 64 + c16 * 8, &sK[buf][w * 16 + j * 8][0]);
      gload_lds16(vt + (size_t)(h * 64 + rg) * S_LD + s0 + c16 * 8, &sV[buf][w * 16 + j * 8][0]);
    }
  };

  stage(0, si * 64);
  __syncthreads();
  int cur = 0;

  for (int ci = si; ci < NCHUNK; ci += NSPLIT) {
    const int s0c = ci * 64;
    if (ci + NSPLIT < NCHUNK) stage(cur ^ 1, (ci + NSPLIT) * 64);

    // ---- packed mask: 64 bits for this (row, chunk) ----
    const uint2 mv = *(const uint2*)(pmT + ((size_t)ci * B_TOT + qrow) * 2);
    // ---- QK^T (raw scores): D[s][q], s reg-mapped, q = q5 ----
    f32x16 sc[2] = {{}, {}};
#pragma unroll
    for (int kc = 0; kc < 4; kc++) {
      const int slot = ((2 * kc + hi) ^ (q5 & 7)) * 8;
      bf16x8 ka0 = ld_frag(&sK[cur][q5][slot]);
      bf16x8 ka1 = ld_frag(&sK[cur][32 + q5][slot]);
      sc[0] = __builtin_amdgcn_mfma_f32_32x32x16_bf16(ka0, qf[kc], sc[0], 0, 0, 0);
      sc[1] = __builtin_amdgcn_mfma_f32_32x32x16_bf16(ka1, qf[kc], sc[1], 0, 0, 0);
    }
    // ---- mask in raw domain: bit pos = (r&3) + 8*(r>>2) + 4*hi within dword b ----
#pragma unroll
    for (int b = 0; b < 2; b++) {
      const uint_t mw = (b ? mv.y : mv.x) >> (4 * hi);
#pragma unroll
      for (int r = 0; r < 16; r++) {
        uint_t bit = mw & (1u << ((r & 3) + 8 * (r >> 2)));
        sc[b][r] = bit ? sc[b][r] : -1e9f;
      }
    }
    // ---- chunk max, raw units (lane-local 32 + 1 shfl) ----
    float mc = fmaxf(sc[0][0], sc[0][1]);
#pragma unroll
    for (int b = 0; b < 2; b++)
#pragma unroll
      for (int r = (b ? 0 : 2); r < 16; r++) mc = fmaxf(mc, sc[b][r]);
    mc = fmaxf(mc, __shfl_xor(mc, 32));
    // ---- rescale when running max grows ----
    if (!__all(mc <= m)) {
      float mn = fmaxf(m, mc);
      float al = exp2f((m - mn) * SC);
      m = mn;
      l *= al;
#pragma unroll
      for (int dc = 0; dc < 2; dc++)
#pragma unroll
        for (int r = 0; r < 16; r++) ctx[dc][r] *= al;
    }
    const float mlg = m * SC;
    // ---- p = exp2(sc*SC - mlg) via fma; pack to bf16 for PV ----
    uint2 pk[2][4];
    float ls = 0.f;
#pragma unroll
    for (int b = 0; b < 2; b++)
#pragma unroll
      for (int j = 0; j < 4; j++) {
        float p0 = exp2f(__builtin_fmaf(sc[b][4 * j + 0], SC, -mlg));
        float p1 = exp2f(__builtin_fmaf(sc[b][4 * j + 1], SC, -mlg));
        float p2 = exp2f(__builtin_fmaf(sc[b][4 * j + 2], SC, -mlg));
        float p3 = exp2f(__builtin_fmaf(sc[b][4 * j + 3], SC, -mlg));
        pk[b][j].x = cvtpk(p0, p1);
        pk[b][j].y = cvtpk(p2, p3);
        ls += (p0 + p1) + (p2 + p3);
      }
    ls += __shfl_xor(ls, 32);
    l += ls;
    // ---- PV: B-frag = P regs (k = hi*4+e), A-frag = V^T b64 reads ----
#pragma unroll
    for (int b = 0; b < 2; b++)
#pragma unroll
      for (int j = 0; j < 4; j++) {
        bf16x4 pb = __builtin_bit_cast(bf16x4, pk[b][j]);
        const int slot = ((4 * b + j) ^ (q5 & 7)) * 8 + hi * 4;
        bf16x4 va0 = *(const bf16x4*)&sV[cur][q5][slot];
        bf16x4 va1 = *(const bf16x4*)&sV[cur][32 + q5][slot];
        ctx[0] = mfma_32x32x8(va0, pb, ctx[0]);
        ctx[1] = mfma_32x32x8(va1, pb, ctx[1]);
      }
    __syncthreads();
    cur ^= 1;
  }
  // ---- write partials ----
  size_t obase = (((size_t)si * B_TOT + qrow) * NHEAD + h) * 64;
#pragma unroll
  for (int dc = 0; dc < 2; dc++)
#pragma unroll
    for (int r = 0; r < 16; r++) {
      int d = dc * 32 + (r & 3) + 8 * (r >> 2) + 4 * hi;
      pc[obase + d] = ctx[dc][r];
    }
  if (lane < 32) {
    size_t base = (((size_t)si * B_TOT + qrow) * NHEAD + h) * 2;
    pml[base] = m * SC;           // log2 units for combine
    pml[base + 1] = l;
  }
}

// ---------------- combine split partials (m,l in log2 domain) ----------------
__global__ void combine_k(const float* __restrict__ pc, const float* __restrict__ pml,
                          const float* __restrict__ vm, u16* __restrict__ ctxb) {
  const int b = blockIdx.x, t = threadIdx.x;
  const int h = t >> 6, d = t & 63;
  float ms[NSPLIT], ls[NSPLIT];
  float M = -3e38f;
#pragma unroll
  for (int si = 0; si < NSPLIT; si++) {
    size_t base = (((size_t)si * B_TOT + b) * NHEAD + h) * 2;
    ms[si] = pml[base];
    ls[si] = pml[base + 1];
    M = fmaxf(M, ms[si]);
  }
  float L = 0.f, a = 0.f;
#pragma unroll
  for (int si = 0; si < NSPLIT; si++) {
    float wgt = exp2f(ms[si] - M);
    L += ls[si] * wgt;
    a += wgt * pc[((((size_t)si * B_TOT + b) * NHEAD + h) << 6) + d];
  }
  float r = (M < -1e8f) ? vm[t] : (a / L);
  ctxb[(size_t)b * 256 + t] = f2bf(r);
}

// ---------------- launch ----------------
extern "C" void kernel_launch(void* const* d_in, const int* in_sizes, int n_in,
                              void* d_out, int out_size, void* d_ws, size_t ws_size,
                              hipStream_t stream) {
  const int*   act = (const int*)d_in[0];
  const float* nc  = (const float*)d_in[1];
  const float* emb = (const float*)d_in[2];
  const float* ipw = (const float*)d_in[3];
  const float* ipb = (const float*)d_in[4];
  const float* opw = (const float*)d_in[5];
  const float* opb = (const float*)d_in[6];
  float* out = (float*)d_out;
  char* ws = (char*)d_ws;

  size_t off = 0;
  auto alloc = [&](size_t bytes) { size_t r0 = off; off = (off + bytes + 255) & ~(size_t)255; return r0; };
  u16*   wqkv = (u16*)(ws + alloc(768 * 256 * 2));
  u16*   wout = (u16*)(ws + alloc(256 * 256 * 2));
  u16*   ncb  = (u16*)(ws + alloc((size_t)B_TOT * 256 * 2));
  u16*   qb   = (u16*)(ws + alloc((size_t)B_TOT * 256 * 2));
  u16*   kbuf = (u16*)(ws + alloc((size_t)S_TOT * 256 * 2));
  u16*   vtb  = (u16*)(ws + alloc((size_t)256 * S_LD * 2));
  float* cmp  = (float*)(ws + alloc(200 * 256 * 4));
  float* vm   = (float*)(ws + alloc(256 * 4));
  float* pml  = (float*)(ws + alloc((size_t)NSPLIT * B_TOT * NHEAD * 2 * 4));
  u16*   ctxb = (u16*)(ws + alloc((size_t)B_TOT * 256 * 2));
  uint_t* pmT = (uint_t*)(ws + alloc((size_t)NCHUNK * B_TOT * 8));
  // union region: embb (10.25 MB, dead after kv-projection) overlaid by pc (32 MB)
  size_t ubase = off;
  u16*   embb = (u16*)(ws + ubase);
  float* pc   = (float*)(ws + ubase);

  convert_all<<<2048, 256, 0, stream>>>(ipw, opw, nc, wqkv, wout, ncb);
  conv_cm<<<200, 256, 0, stream>>>(emb, embb, cmp);
  zero_vt_pad<<<32, 256, 0, stream>>>(vtb);
  pack_k<<<(B_TOT * NCHUNK) / 4, 256, 0, stream>>>(act, pmT);
  vmean2_k<<<16, 256, 0, stream>>>(cmp, ipw, ipb, vm);
  gemm_bt<0><<<dim3(16, 4), 256, 0, stream>>>(ncb, wqkv, ipb, B_TOT, qb, nullptr);
  gemm_kv<<<dim3(157, 8), 256, 0, stream>>>(embb, wqkv + 256 * 256, ipb + 256, kbuf, vtb);
  attn_k<<<dim3(NSPLIT, B_TOT / 128, NHEAD), 256, 0, stream>>>(qb, kbuf, vtb, pmT, pc, pml);
  combine_k<<<B_TOT, 256, 0, stream>>>(pc, pml, vm, ctxb);
  gemm_bt<2><<<dim3(16, 4), 256, 0, stream>>>(ctxb, wout, opb, B_TOT, nullptr, out);
}

// Round 6
// 145.399 us; speedup vs baseline: 2.1174x; 1.0658x over previous
//
#include <hip/hip_runtime.h>

typedef unsigned int uint_t;
typedef unsigned short u16;
typedef __attribute__((ext_vector_type(4))) float f32x4;
typedef __attribute__((ext_vector_type(16))) float f32x16;
typedef __attribute__((ext_vector_type(8))) __bf16 bf16x8;
typedef __attribute__((ext_vector_type(4))) __bf16 bf16x4;

#define S_TOT 20000
#define S_LD  20032   // padded V^T row stride / padded K rows
#define B_TOT 1024
#define NHEAD 4
#define NSPLIT 32
#define NCHUNK 313    // ceil(20000/64)

__device__ __forceinline__ u16 f2bf(float x) {
  uint_t u = __builtin_bit_cast(uint_t, x);
  u += 0x7FFFu + ((u >> 16) & 1u);
  return (u16)(u >> 16);
}

__device__ __forceinline__ uint_t cvtpk(float lo, float hi) {
  uint_t r;
  asm("v_cvt_pk_bf16_f32 %0, %1, %2" : "=v"(r) : "v"(lo), "v"(hi));
  return r;
}

__device__ __forceinline__ bf16x8 ld_frag(const u16* p) {
  return __builtin_bit_cast(bf16x8, *(const uint4*)p);
}

__device__ __forceinline__ void gload_lds16(const void* g, void* l) {
  __builtin_amdgcn_global_load_lds((const __attribute__((address_space(1))) unsigned int*)g,
                                   (__attribute__((address_space(3))) unsigned int*)l, 16, 0, 0);
}

__device__ __forceinline__ f32x16 mfma_32x32x8(bf16x4 a, bf16x4 b, f32x16 c) {
  asm("v_mfma_f32_32x32x8_bf16 %0, %1, %2, %0" : "+v"(c) : "v"(a), "v"(b));
  return c;
}

// ---------------- fused: mask bit-pack + f32->bf16 weight/nc conversion ----------------
// blocks [0,512): convert 524288 f32 (ipw|opw|nc) as float4.
// blocks [512, 512+80128): pack_k — 1 wave per (row,chunk), 64 bits via ballot.
__global__ void pack_conv(const int* __restrict__ act, uint_t* __restrict__ pmT,
                          const float* __restrict__ ipw, const float* __restrict__ opw,
                          const float* __restrict__ nc,
                          u16* __restrict__ wqkv, u16* __restrict__ wout, u16* __restrict__ ncb) {
  const int bx = blockIdx.x;
  if (bx < 512) {
    int i = (bx * 256 + threadIdx.x) * 4;
    const float* src; u16* dst;
    if (i < 196608)      { src = ipw + i;            dst = wqkv + i; }
    else if (i < 262144) { src = opw + (i - 196608); dst = wout + (i - 196608); }
    else                 { src = nc  + (i - 262144); dst = ncb  + (i - 262144); }
    float4 v = *(const float4*)src;
    uint2 o;
    o.x = f2bf(v.x) | ((uint_t)f2bf(v.y) << 16);
    o.y = f2bf(v.z) | ((uint_t)f2bf(v.w) << 16);
    *(uint2*)dst = o;
    return;
  }
  int gw = ((bx - 512) * 256 + threadIdx.x) >> 6;
  int lane = threadIdx.x & 63;
  int row = gw / NCHUNK, ci = gw - row * NCHUNK;
  if (row >= B_TOT) return;
  int s = ci * 64 + lane;
  int v = (s < S_TOT) ? act[(size_t)row * S_TOT + s] : 0;
  unsigned long long b = __ballot(v > 0);
  if (lane == 0) {
    uint2 o; o.x = (uint_t)b; o.y = (uint_t)(b >> 32);
    *(uint2*)(pmT + ((size_t)ci * B_TOT + row) * 2) = o;
  }
}

// ---------------- fused: emb f32->bf16 convert + column partial sums ----------------
__global__ void conv_cm(const float* __restrict__ emb, u16* __restrict__ embb,
                        float* __restrict__ cmp) {
  __shared__ float4 rbuf[256];
  const int t = threadIdx.x, p = blockIdx.x;
  const int c4 = (t & 63) * 4, rg = t >> 6;
  float s0 = 0.f, s1 = 0.f, s2 = 0.f, s3 = 0.f;
#pragma unroll 4
  for (int i = 0; i < 25; i++) {
    int r = p * 100 + rg + i * 4;
    float4 v = *(const float4*)(emb + (size_t)r * 256 + c4);
    uint2 o;
    o.x = f2bf(v.x) | ((uint_t)f2bf(v.y) << 16);
    o.y = f2bf(v.z) | ((uint_t)f2bf(v.w) << 16);
    *(uint2*)(embb + (size_t)r * 256 + c4) = o;
    s0 += v.x; s1 += v.y; s2 += v.z; s3 += v.w;
  }
  rbuf[t] = make_float4(s0, s1, s2, s3);
  __syncthreads();
  if (t < 64) {
    float4 a = rbuf[t], b = rbuf[t + 64], c = rbuf[t + 128], d = rbuf[t + 192];
    float4 o = make_float4(a.x + b.x + c.x + d.x, a.y + b.y + c.y + d.y,
                           a.z + b.z + c.z + d.z, a.w + b.w + c.w + d.w);
    *(float4*)(cmp + p * 256 + t * 4) = o;
  }
}

// zero the padded tail columns of V^T (must be finite: 0xAA-or-garbage * 0 could be NaN)
__global__ void zero_vt_pad(u16* __restrict__ vt) {
  int i = blockIdx.x * 256 + threadIdx.x;           // 8192 = 256 rows * 32
  int d = i >> 5, j = i & 31;
  vt[(size_t)d * S_LD + S_TOT + j] = 0;
}

// ---------------- v_mean = (mean_emb @ Wv^T + bv), parallel ----------------
__global__ void vmean2_k(const float* __restrict__ cmp, const float* __restrict__ ipw,
                         const float* __restrict__ ipb, float* __restrict__ vm) {
  __shared__ float mean[256];
  __shared__ float red[256];
  const int t = threadIdx.x;
  float s = 0.f;
#pragma unroll 8
  for (int p = 0; p < 200; p++) s += cmp[p * 256 + t];
  mean[t] = s * (1.0f / 20000.0f);
  __syncthreads();
  const int row = blockIdx.x * 16 + (t >> 4), l16 = t & 15;
  const float* wv = ipw + (size_t)(512 + row) * 256 + l16 * 16;
  float a = 0.f;
#pragma unroll
  for (int j = 0; j < 16; j++) a += mean[l16 * 16 + j] * wv[j];
  red[t] = a;
  __syncthreads();
  if (l16 == 0) {
    float s2 = 0.f;
#pragma unroll
    for (int j = 0; j < 16; j++) s2 += red[t + j];
    vm[row] = s2 + ipb[512 + row];
  }
}

// ---------------- small B^T GEMM (q-proj, out-proj): C[M x 256] ----------------
template<int MODE>   // 0: out bf16 (scaled), 2: out f32
__launch_bounds__(256)
__global__ void gemm_bt(const u16* __restrict__ A, const u16* __restrict__ W,
                        const float* __restrict__ bias, int M,
                        u16* __restrict__ ob, float* __restrict__ of, float oscale) {
  __shared__ __align__(16) u16 sA[64][40];
  __shared__ __align__(16) u16 sW[64][40];
  const int t = threadIdx.x;
  const int w = t >> 6, lane = t & 63, lr = lane & 15, lg = lane >> 4;
  const int m0 = blockIdx.x * 64, n0 = blockIdx.y * 64;
  const int r = t >> 2, kc = (t & 3) * 8;
  f32x4 acc[4] = {};
  int ga = m0 + r; if (ga > M - 1) ga = M - 1;
  const u16* ap = A + (size_t)ga * 256;
  const u16* wp = W + (size_t)(n0 + r) * 256;
  for (int k0 = 0; k0 < 256; k0 += 32) {
    *(uint4*)&sA[r][kc] = *(const uint4*)(ap + k0 + kc);
    *(uint4*)&sW[r][kc] = *(const uint4*)(wp + k0 + kc);
    __syncthreads();
    bf16x8 af = ld_frag(&sA[16 * w + lr][lg * 8]);
#pragma unroll
    for (int nf = 0; nf < 4; nf++) {
      bf16x8 bfr = ld_frag(&sW[16 * nf + lr][lg * 8]);
      acc[nf] = __builtin_amdgcn_mfma_f32_16x16x32_bf16(af, bfr, acc[nf], 0, 0, 0);
    }
    __syncthreads();
  }
  const int rbase = m0 + 16 * w + lg * 4;
#pragma unroll
  for (int nf = 0; nf < 4; nf++) {
    const int n = n0 + nf * 16 + lr;
    const float bi = bias[n];
    if (MODE == 0) {
#pragma unroll
      for (int g = 0; g < 4; g++)
        if (rbase + g < M) ob[(size_t)(rbase + g) * 256 + n] = f2bf((acc[nf][g] + bi) * oscale);
    } else {
#pragma unroll
      for (int g = 0; g < 4; g++)
        if (rbase + g < M) of[(size_t)(rbase + g) * 256 + n] = acc[nf][g] + bi;
    }
  }
}

// ---------------- KV projection: C[20000 x 512] = embb @ Wkv^T + b ----------------
__launch_bounds__(256, 3)
__global__ void gemm_kv(const u16* __restrict__ A, const u16* __restrict__ W,
                        const float* __restrict__ bias,
                        u16* __restrict__ kb, u16* __restrict__ vtb) {
  __shared__ __align__(16) u16 sA[2][128][64];
  __shared__ __align__(16) u16 sW[2][64][64];
  const int t = threadIdx.x, w = t >> 6, lane = t & 63;
  const int q5 = lane & 31, hi = lane >> 5;
  const int wr = w >> 1, wc = w & 1;
  const int m0 = blockIdx.x * 128, n0 = blockIdx.y * 64;

  auto stage = [&](int buf, int k0) {
#pragma unroll
    for (int j = 0; j < 4; j++) {           // A: 1024 16B-chunks
      int c = j * 256 + w * 64 + lane;
      int row = c >> 3, slot = c & 7;
      int gm = m0 + row; if (gm > S_TOT - 1) gm = S_TOT - 1;
      gload_lds16(A + (size_t)gm * 256 + k0 + ((slot ^ (row & 7)) * 8),
                  &sA[buf][0][0] + (size_t)(j * 256 + w * 64) * 8);
    }
#pragma unroll
    for (int j = 0; j < 2; j++) {           // W: 512 16B-chunks
      int c = j * 256 + w * 64 + lane;
      int row = c >> 3, slot = c & 7;
      gload_lds16(W + (size_t)(n0 + row) * 256 + k0 + ((slot ^ (row & 7)) * 8),
                  &sW[buf][0][0] + (size_t)(j * 256 + w * 64) * 8);
    }
  };

  f32x16 acc[2] = {{}, {}};
  stage(0, 0);
  __syncthreads();
  for (int ks = 0; ks < 4; ks++) {
    const int buf = ks & 1;
    if (ks < 3) stage(buf ^ 1, (ks + 1) * 64);
#pragma unroll
    for (int k4 = 0; k4 < 4; k4++) {
      const int rowW = wc * 32 + q5;
      bf16x8 wf = ld_frag(&sW[buf][rowW][((2 * k4 + hi) ^ (rowW & 7)) * 8]);
#pragma unroll
      for (int blk = 0; blk < 2; blk++) {
        const int rowA = wr * 64 + blk * 32 + q5;
        bf16x8 af = ld_frag(&sA[buf][rowA][((2 * k4 + hi) ^ (rowA & 7)) * 8]);
        acc[blk] = __builtin_amdgcn_mfma_f32_32x32x16_bf16(af, wf, acc[blk], 0, 0, 0);
      }
    }
    __syncthreads();
  }
  const int n = n0 + wc * 32 + q5;
  const float bi = bias[n];
  if (n < 256) {
#pragma unroll
    for (int blk = 0; blk < 2; blk++)
#pragma unroll
      for (int r = 0; r < 16; r++) {
        int mrow = m0 + wr * 64 + blk * 32 + (r & 3) + 8 * (r >> 2) + 4 * hi;
        if (mrow < S_TOT) kb[(size_t)mrow * 256 + n] = f2bf(acc[blk][r] + bi);
      }
  } else {
    const int vr = n - 256;
#pragma unroll
    for (int blk = 0; blk < 2; blk++)
#pragma unroll
      for (int g = 0; g < 4; g++) {
        int mb = m0 + wr * 64 + blk * 32 + 8 * g + 4 * hi;
        u16 b4[4];
#pragma unroll
        for (int j = 0; j < 4; j++) b4[j] = f2bf(acc[blk][4 * g + j] + bi);
        if (mb + 3 < S_TOT) {
          uint2 p2; p2.x = b4[0] | ((uint_t)b4[1] << 16); p2.y = b4[2] | ((uint_t)b4[3] << 16);
          *(uint2*)&vtb[(size_t)vr * S_LD + mb] = p2;
        } else {
#pragma unroll
          for (int j = 0; j < 4; j++) if (mb + j < S_TOT) vtb[(size_t)vr * S_LD + mb + j] = b4[j];
        }
      }
  }
}

// ---------------- flash attention: fixed-reference softmax (M=0), additive splits ----------------
// Q pre-scaled by 0.125*log2e, so QK^T output is already log2-domain: p = exp2(sc).
// Unroll-by-2 chunk loop -> all LDS fragment addresses loop-invariant.
__launch_bounds__(256, 4)
__global__ void attn_k(const u16* __restrict__ qb, const u16* __restrict__ kb,
                       const u16* __restrict__ vt, const uint_t* __restrict__ pmT,
                       float* __restrict__ pc, float* __restrict__ pl) {
  __shared__ __align__(16) u16 sK[2][64][64];
  __shared__ __align__(16) u16 sV[2][64][64];
  const int t = threadIdx.x;
  const int w = t >> 6, lane = t & 63;
  const int q5 = lane & 31, hi = lane >> 5;
  const int si = blockIdx.x, bt = blockIdx.y, h = blockIdx.z;
  const int qrow = bt * 128 + w * 32 + q5;

  // Q B-fragments (loaded once): n=q5, k = kc*16 + hi*8 + e
  bf16x8 qf[4];
#pragma unroll
  for (int kc = 0; kc < 4; kc++)
    qf[kc] = ld_frag(qb + (size_t)qrow * 256 + h * 64 + kc * 16 + hi * 8);

  f32x16 ctx[2] = {{}, {}};
  float l = 0.f;

  // staging pointers, strength-reduced (+= const per chunk)
  const int rg = w * 16 + (lane >> 3);
  const int c16 = (lane & 7) ^ ((lane >> 3) & 7);
  const u16* kst = kb + (size_t)(si * 64 + rg) * 256 + h * 64 + c16 * 8;
  const u16* vst = vt + (size_t)(h * 64 + rg) * S_LD + si * 64 + c16 * 8;
  const uint_t* mptr = pmT + ((size_t)si * B_TOT + qrow) * 2;
  const size_t KSTEP = (size_t)NSPLIT * 64 * 256;
  const int    VSTEP = NSPLIT * 64;
  const size_t MSTEP = (size_t)NSPLIT * B_TOT * 2;

  auto stage = [&](int buf) {
    gload_lds16(kst,           &sK[buf][w * 16][0]);
    gload_lds16(kst + 8 * 256, &sK[buf][w * 16 + 8][0]);
    gload_lds16(vst,           &sV[buf][w * 16][0]);
    gload_lds16(vst + 8 * S_LD, &sV[buf][w * 16 + 8][0]);
    kst += KSTEP; vst += VSTEP;
  };

  auto body = [&](int buf) {
    const uint2 mv = *(const uint2*)mptr; mptr += MSTEP;
    // QK^T: D[s][q], s reg-mapped, q = q5 (log2-domain scores)
    f32x16 sc0 = {}, sc1 = {};
#pragma unroll
    for (int kc = 0; kc < 4; kc++) {
      const int slot = ((2 * kc + hi) ^ (q5 & 7)) * 8;
      bf16x8 ka0 = ld_frag(&sK[buf][q5][slot]);
      bf16x8 ka1 = ld_frag(&sK[buf][32 + q5][slot]);
      sc0 = __builtin_amdgcn_mfma_f32_32x32x16_bf16(ka0, qf[kc], sc0, 0, 0, 0);
      sc1 = __builtin_amdgcn_mfma_f32_32x32x16_bf16(ka1, qf[kc], sc1, 0, 0, 0);
    }
    // mask: bit = (r&3) + 8*(r>>2) within dword, nibble-offset 4*hi
    const uint_t mw0 = mv.x >> (4 * hi), mw1 = mv.y >> (4 * hi);
#pragma unroll
    for (int r = 0; r < 16; r++) {
      const uint_t bsel = 1u << ((r & 3) + 8 * (r >> 2));
      sc0[r] = (mw0 & bsel) ? sc0[r] : -1e9f;
      sc1[r] = (mw1 & bsel) ? sc1[r] : -1e9f;
    }
    // p = exp2(sc) (fixed reference M=0); pack to bf16; l-sum
    uint2 pk[2][4];
    float ls = 0.f;
#pragma unroll
    for (int j = 0; j < 4; j++) {
      float a0 = exp2f(sc0[4 * j + 0]), a1 = exp2f(sc0[4 * j + 1]);
      float a2 = exp2f(sc0[4 * j + 2]), a3 = exp2f(sc0[4 * j + 3]);
      float b0 = exp2f(sc1[4 * j + 0]), b1 = exp2f(sc1[4 * j + 1]);
      float b2 = exp2f(sc1[4 * j + 2]), b3 = exp2f(sc1[4 * j + 3]);
      pk[0][j].x = cvtpk(a0, a1); pk[0][j].y = cvtpk(a2, a3);
      pk[1][j].x = cvtpk(b0, b1); pk[1][j].y = cvtpk(b2, b3);
      ls += (a0 + a1) + (a2 + a3) + (b0 + b1) + (b2 + b3);
    }
    ls += __shfl_xor(ls, 32);
    l += ls;
    // PV: B-frag = P regs (k = hi*4+e), A-frag = V^T b64 reads
#pragma unroll
    for (int b = 0; b < 2; b++)
#pragma unroll
      for (int j = 0; j < 4; j++) {
        bf16x4 pb = __builtin_bit_cast(bf16x4, pk[b][j]);
        const int slot = ((4 * b + j) ^ (q5 & 7)) * 8 + hi * 4;
        bf16x4 va0 = *(const bf16x4*)&sV[buf][q5][slot];
        bf16x4 va1 = *(const bf16x4*)&sV[buf][32 + q5][slot];
        ctx[0] = mfma_32x32x8(va0, pb, ctx[0]);
        ctx[1] = mfma_32x32x8(va1, pb, ctx[1]);
      }
  };

  stage(0);
  __syncthreads();
  int ci = si;
  for (;;) {
    if (ci + NSPLIT < NCHUNK) stage(1);
    body(0);
    __syncthreads();
    ci += NSPLIT;
    if (ci >= NCHUNK) break;
    if (ci + NSPLIT < NCHUNK) stage(0);
    body(1);
    __syncthreads();
    ci += NSPLIT;
    if (ci >= NCHUNK) break;
  }

  // write partials: d = dc*32 + (r&3) + 8*(r>>2) + 4*hi, q = q5
  size_t obase = (((size_t)si * B_TOT + qrow) * NHEAD + h) * 64;
#pragma unroll
  for (int dc = 0; dc < 2; dc++)
#pragma unroll
    for (int r = 0; r < 16; r++) {
      int d = dc * 32 + (r & 3) + 8 * (r >> 2) + 4 * hi;
      pc[obase + d] = ctx[dc][r];
    }
  if (lane < 32)
    pl[((size_t)si * B_TOT + qrow) * NHEAD + h] = l;
}

// ---------------- combine: pure sums (fixed-reference splits are additive) ----------------
__global__ void combine_k(const float* __restrict__ pc, const float* __restrict__ pl,
                          const float* __restrict__ vm, u16* __restrict__ ctxb) {
  const int b = blockIdx.x, t = threadIdx.x;
  const int h = t >> 6, d = t & 63;
  float L = 0.f, a = 0.f;
#pragma unroll
  for (int si = 0; si < NSPLIT; si++) {
    size_t base = ((size_t)si * B_TOT + b) * NHEAD + h;
    L += pl[base];
    a += pc[(base << 6) + d];
  }
  float r = (L == 0.f) ? vm[t] : (a / L);
  ctxb[(size_t)b * 256 + t] = f2bf(r);
}

// ---------------- launch ----------------
extern "C" void kernel_launch(void* const* d_in, const int* in_sizes, int n_in,
                              void* d_out, int out_size, void* d_ws, size_t ws_size,
                              hipStream_t stream) {
  const int*   act = (const int*)d_in[0];
  const float* nc  = (const float*)d_in[1];
  const float* emb = (const float*)d_in[2];
  const float* ipw = (const float*)d_in[3];
  const float* ipb = (const float*)d_in[4];
  const float* opw = (const float*)d_in[5];
  const float* opb = (const float*)d_in[6];
  float* out = (float*)d_out;
  char* ws = (char*)d_ws;

  size_t off = 0;
  auto alloc = [&](size_t bytes) { size_t r0 = off; off = (off + bytes + 255) & ~(size_t)255; return r0; };
  u16*   wqkv = (u16*)(ws + alloc(768 * 256 * 2));
  u16*   wout = (u16*)(ws + alloc(256 * 256 * 2));
  u16*   ncb  = (u16*)(ws + alloc((size_t)B_TOT * 256 * 2));
  u16*   qb   = (u16*)(ws + alloc((size_t)B_TOT * 256 * 2));
  u16*   kbuf = (u16*)(ws + alloc((size_t)S_LD * 256 * 2));   // padded rows (stage reads past 20000)
  u16*   vtb  = (u16*)(ws + alloc((size_t)256 * S_LD * 2));
  float* cmp  = (float*)(ws + alloc(200 * 256 * 4));
  float* vm   = (float*)(ws + alloc(256 * 4));
  float* pl   = (float*)(ws + alloc((size_t)NSPLIT * B_TOT * NHEAD * 4));
  u16*   ctxb = (u16*)(ws + alloc((size_t)B_TOT * 256 * 2));
  uint_t* pmT = (uint_t*)(ws + alloc((size_t)NCHUNK * B_TOT * 8));
  // union region: embb (10.25 MB, dead after kv-projection) overlaid by pc (33.6 MB)
  size_t ubase = off;
  u16*   embb = (u16*)(ws + ubase);
  float* pc   = (float*)(ws + ubase);

  const float QSC = 0.125f * 1.44269504089f;   // (1/sqrt(64)) * log2(e), folded into Q

  pack_conv<<<512 + (B_TOT * NCHUNK) / 4, 256, 0, stream>>>(act, pmT, ipw, opw, nc, wqkv, wout, ncb);
  conv_cm<<<200, 256, 0, stream>>>(emb, embb, cmp);
  zero_vt_pad<<<32, 256, 0, stream>>>(vtb);
  vmean2_k<<<16, 256, 0, stream>>>(cmp, ipw, ipb, vm);
  gemm_bt<0><<<dim3(16, 4), 256, 0, stream>>>(ncb, wqkv, ipb, B_TOT, qb, nullptr, QSC);
  gemm_kv<<<dim3(157, 8), 256, 0, stream>>>(embb, wqkv + 256 * 256, ipb + 256, kbuf, vtb);
  attn_k<<<dim3(NSPLIT, B_TOT / 128, NHEAD), 256, 0, stream>>>(qb, kbuf, vtb, pmT, pc, pl);
  combine_k<<<B_TOT, 256, 0, stream>>>(pc, pl, vm, ctxb);
  gemm_bt<2><<<dim3(16, 4), 256, 0, stream>>>(ctxb, wout, opb, B_TOT, nullptr, out, 1.0f);
}